// Round 1
// baseline (201.356 us; speedup 1.0000x reference)
//
#include <hip/hip_runtime.h>

#define DM 1024
#define HID 64
#define NSTEP 6
#define RSTEP (1.0f/6.0f)

using short8  = __attribute__((ext_vector_type(8))) short;
using short4v = __attribute__((ext_vector_type(4))) short;
using f32x4   = __attribute__((ext_vector_type(4))) float;

// workspace byte offsets
#define WS_W1P 0          // 1024x64 bf16 packed A-frags (131072 B)
#define WS_W2P 131072     // 64x1024 bf16 packed A-frags (131072 B)
#define WS_GP  262144     // 64x64 bf16 packed A-frags (8192 B)
#define WS_U   270336     // 64 f32  (u = b2 @ W1k)

// LDS byte offsets
#define L_ZH 0            // [32][1024] bf16 hi, XOR-swizzled (65536)
#define L_ZL 65536        // [32][1024] bf16 lo residual     (65536)
#define L_H0 131072       // H ping  [32][72] bf16 (4608)
#define L_H1 135680       // H pong
#define L_HB 140288       // Hb = (h/6)*Hsum
#define LDS_TOTAL 144896
#define HPITCH 144        // bytes per H row (72 bf16, pad vs bank conflicts)

__device__ __forceinline__ float bf2f(short s) {
    union { unsigned u; float f; } v;
    v.u = ((unsigned)(unsigned short)s) << 16;
    return v.f;
}
__device__ __forceinline__ short f2bf(float f) {   // round-to-nearest-even
    union { float f; unsigned u; } v;
    v.f = f;
    unsigned u = v.u;
    u += 0x7FFFu + ((u >> 16) & 1u);
    return (short)(u >> 16);
}
__device__ __forceinline__ float ftanh(float x) {
    x = fminf(fmaxf(x, -10.f), 10.f);
    float e = __expf(2.f * x);
    return __fdividef(e - 1.f, e + 1.f);
}

// ---------------- prep: pack weights to MFMA fragment layout ----------------
// A-frag layout for mfma_f32_16x16x32_bf16: lane l holds M-row (l&15),
// k = (l>>4)*8 + i (8 consecutive k). Packed so each lane loads one short8.
__global__ void k_prep(const float* __restrict__ W1, const float* __restrict__ W2,
                       const float* __restrict__ b2,
                       short* __restrict__ W1P, short* __restrict__ W2P,
                       short* __restrict__ GP, float* __restrict__ U) {
    int b = blockIdx.x;
    int l = threadIdx.x;           // 64 threads
    if (b < 128) {                 // W1k (1024x64) -> W1P[kk<32][c<4][l][8]
        int kk = b >> 2, c = b & 3;
        int col = c * 16 + (l & 15);
        int kb = kk * 32 + ((l >> 4) << 3);
        short8 v;
        #pragma unroll
        for (int i = 0; i < 8; ++i) v[i] = f2bf(W1[(kb + i) * HID + col]);
        *(short8*)(W1P + (((kk * 4 + c) * 64) + l) * 8) = v;
    } else if (b < 256) {          // W2 (64x1024) -> W2P[kk2<2][ct<64][l][8]
        int bb = b - 128;
        int kk2 = bb >> 6, ct = bb & 63;
        int col = ct * 16 + (l & 15);
        int kb = kk2 * 32 + ((l >> 4) << 3);
        short8 v;
        #pragma unroll
        for (int i = 0; i < 8; ++i) v[i] = f2bf(W2[(kb + i) * DM + col]);
        *(short8*)(W2P + (((kk2 * 64 + ct) * 64) + l) * 8) = v;
    } else if (b < 320) {          // G[j][i] = sum_d W2[j][d]*W1[d][i]; j = b-256
        int j = b - 256;
        float acc = 0.f;
        #pragma unroll 8
        for (int d = 0; d < DM; ++d) acc += W2[j * DM + d] * W1[d * HID + l];
        int kk = j >> 5, lk = (j >> 3) & 3, ii = j & 7, c = l >> 4, lo = l & 15;
        GP[(((kk * 4 + c) * 64) + lk * 16 + lo) * 8 + ii] = f2bf(acc);
    } else {                       // u[i] = sum_d b2[d]*W1[d][i]
        float acc = 0.f;
        #pragma unroll 8
        for (int d = 0; d < DM; ++d) acc += b2[d] * W1[d * HID + l];
        U[l] = acc;
    }
}

// ---------------- fused RK4 neural-ODE kernel ----------------
// Block: 512 thr (8 waves), owns 32 rows of z for all 6 RK4 steps.
// Wave w: GEMM1/stage tile (r = w>>2 row-stripe, c = w&3 hid col-tile);
//         GEMM2 col-range [w*128, w*128+128) over both stripes.
// MFMA convention: first operand = packed W (A, M = hid/z-col), second = z/H
// rows (B, N = z-row). D: m = (lane>>4)*4+reg (col), n = lane&15 (row).
__global__ __launch_bounds__(512, 2) void k_ode(
        const float* __restrict__ X, const float* __restrict__ W1,
        const float* __restrict__ b1, const float* __restrict__ b2,
        const short* __restrict__ W1P, const short* __restrict__ W2P,
        const short* __restrict__ GP, const float* __restrict__ U,
        float* __restrict__ OUT) {
    extern __shared__ char smem[];
    const int t = threadIdx.x;
    const int lane = t & 63;
    const int w = t >> 6;
    const int rw = w >> 2, cw = w & 3;
    const int hq = lane >> 4;
    const int l15 = lane & 15;
    const int srow = rw * 16 + l15;          // z-row for GEMM1/stages
    const int hcol0 = cw * 16 + hq * 4;      // hid-col base for this lane's D regs
    const size_t row0 = (size_t)blockIdx.x * 32;

    // persistent per-lane constants (L2-hot broadcasts)
    f32x4 u4   = *(const f32x4*)(U + hcol0);
    f32x4 b14  = *(const f32x4*)(b1 + hcol0);
    f32x4 w1t4 = *(const f32x4*)(W1 + DM * HID + hcol0);   // time row of W1
    short8 gf0 = *(const short8*)(GP + (cw * 64 + lane) * 8);
    short8 gf1 = *(const short8*)(GP + ((4 + cw) * 64 + lane) * 8);
    short8 w2f[2][8];                         // W2 fragments pinned in VGPRs
    #pragma unroll
    for (int kk2 = 0; kk2 < 2; ++kk2)
        #pragma unroll
        for (int q = 0; q < 8; ++q)
            w2f[kk2][q] = *(const short8*)(W2P + ((kk2 * 64 + (w * 8 + q)) * 64 + lane) * 8);

    // ---- load x -> zh/zl (bf16 hi + residual), XOR-swizzled ----
    {
        int r = t >> 4, c4 = t & 15;
        int sw = ((r ^ (r >> 3)) & 7) << 4;
        const f32x4* xs = (const f32x4*)(X + (row0 + r) * DM);
        #pragma unroll 4
        for (int jj = 0; jj < 16; ++jj) {
            int cc = c4 + 16 * jj;           // float4 chunk index in row
            f32x4 v = xs[cc];
            short4v hh, ll;
            #pragma unroll
            for (int j = 0; j < 4; ++j) {
                short h = f2bf(v[j]);
                hh[j] = h;
                ll[j] = f2bf(v[j] - bf2f(h));
            }
            int a = ((r << 11) + (cc << 3)) ^ sw;
            *(short4v*)(smem + L_ZH + a) = hh;
            *(short4v*)(smem + L_ZL + a) = ll;
        }
    }
    __syncthreads();

    const int sw_s = ((srow ^ (srow >> 3)) & 7) << 4;

    for (int s = 0; s < NSTEP; ++s) {
        float tcur = RSTEP * (float)s;

        // P1: sz = (z @ W1k) tile; K=1024 in 32 slices
        f32x4 sz = (f32x4){0.f, 0.f, 0.f, 0.f};
        {
            const short8* wp = (const short8*)W1P + (cw * 64 + lane);
            int zb = (srow << 11) + (hq << 4);
            #pragma unroll 4
            for (int kk = 0; kk < 32; ++kk) {
                short8 zf = *(const short8*)(smem + L_ZH + ((zb + (kk << 6)) ^ sw_s));
                short8 wf = wp[kk * 256];
                sz = __builtin_amdgcn_mfma_f32_16x16x32_bf16(wf, zf, sz, 0, 0, 0);
            }
        }

        // P2: stage 1  H1 = tanh(sz + t*w1t + b1)
        f32x4 hsum;
        {
            short4v hc;
            #pragma unroll
            for (int j = 0; j < 4; ++j) {
                float T = sz[j] + tcur * w1t4[j] + b14[j];
                float h = ftanh(T);
                hsum[j] = h;
                hc[j] = f2bf(h);
            }
            *(short4v*)(smem + L_H0 + srow * HPITCH + hcol0 * 2) = hc;
        }
        __syncthreads();

        // P3..P5: stages 2..4 via tiny H@G GEMM (G = W2@W1k)
        #pragma unroll
        for (int st = 0; st < 3; ++st) {
            const float c_i = (st == 2) ? RSTEP : (0.5f * RSTEP);
            const float t_i = tcur + ((st == 2) ? RSTEP : (0.5f * RSTEP));
            const float w_i = (st == 2) ? 1.f : 2.f;
            const int rbuf = (st & 1) ? L_H1 : L_H0;
            const int wbuf = (st & 1) ? L_H0 : L_H1;

            f32x4 dd = (f32x4){0.f, 0.f, 0.f, 0.f};
            {
                short8 hf0 = *(const short8*)(smem + rbuf + srow * HPITCH + (hq << 4));
                short8 hf1 = *(const short8*)(smem + rbuf + srow * HPITCH + 64 + (hq << 4));
                dd = __builtin_amdgcn_mfma_f32_16x16x32_bf16(gf0, hf0, dd, 0, 0, 0);
                dd = __builtin_amdgcn_mfma_f32_16x16x32_bf16(gf1, hf1, dd, 0, 0, 0);
            }
            short4v hc;
            #pragma unroll
            for (int j = 0; j < 4; ++j) {
                float T = sz[j] + c_i * (dd[j] + u4[j]) + t_i * w1t4[j] + b14[j];
                float h = ftanh(T);
                hsum[j] += w_i * h;
                hc[j] = f2bf(h);
            }
            if (st < 2) {
                *(short4v*)(smem + wbuf + srow * HPITCH + hcol0 * 2) = hc;
            } else {   // Hb = (h/6) * Hsum, ready as GEMM2 B-operand
                short4v hb4;
                #pragma unroll
                for (int j = 0; j < 4; ++j) hb4[j] = f2bf(hsum[j] * (RSTEP / 6.f));
                *(short4v*)(smem + L_HB + srow * HPITCH + hcol0 * 2) = hb4;
            }
            __syncthreads();
        }

        // P6: z += Hb @ W2 + h*b2   (wave w owns cols [w*128, w*128+128))
        {
            short8 hbf[2][2];
            #pragma unroll
            for (int r2 = 0; r2 < 2; ++r2)
                #pragma unroll
                for (int kk2 = 0; kk2 < 2; ++kk2)
                    hbf[r2][kk2] = *(const short8*)(smem + L_HB +
                        (r2 * 16 + l15) * HPITCH + kk2 * 64 + (hq << 4));

            #pragma unroll 2
            for (int q = 0; q < 8; ++q) {
                int ct = w * 8 + q;
                int zc = ct * 16 + hq * 4;
                f32x4 b2v = *(const f32x4*)(b2 + zc);
                #pragma unroll
                for (int r2 = 0; r2 < 2; ++r2) {
                    f32x4 p = (f32x4){0.f, 0.f, 0.f, 0.f};
                    p = __builtin_amdgcn_mfma_f32_16x16x32_bf16(w2f[0][q], hbf[r2][0], p, 0, 0, 0);
                    p = __builtin_amdgcn_mfma_f32_16x16x32_bf16(w2f[1][q], hbf[r2][1], p, 0, 0, 0);
                    int zr = r2 * 16 + l15;
                    int a = ((zr << 11) + (zc << 1)) ^ (((zr ^ (zr >> 3)) & 7) << 4);
                    short4v oh = *(short4v*)(smem + L_ZH + a);
                    short4v ol = *(short4v*)(smem + L_ZL + a);
                    short4v nh, nl;
                    #pragma unroll
                    for (int j = 0; j < 4; ++j) {
                        float v = bf2f(oh[j]) + bf2f(ol[j]) + p[j] + RSTEP * b2v[j];
                        short h = f2bf(v);
                        nh[j] = h;
                        nl[j] = f2bf(v - bf2f(h));
                    }
                    *(short4v*)(smem + L_ZH + a) = nh;
                    *(short4v*)(smem + L_ZL + a) = nl;
                }
            }
        }
        __syncthreads();
    }

    // ---- store z -> OUT ----
    {
        int r = t >> 4, c4 = t & 15;
        int sw = ((r ^ (r >> 3)) & 7) << 4;
        f32x4* od = (f32x4*)(OUT + (row0 + r) * DM);
        #pragma unroll 4
        for (int jj = 0; jj < 16; ++jj) {
            int cc = c4 + 16 * jj;
            int a = ((r << 11) + (cc << 3)) ^ sw;
            short4v hh = *(short4v*)(smem + L_ZH + a);
            short4v ll = *(short4v*)(smem + L_ZL + a);
            f32x4 v;
            #pragma unroll
            for (int j = 0; j < 4; ++j) v[j] = bf2f(hh[j]) + bf2f(ll[j]);
            od[cc] = v;
        }
    }
}

extern "C" void kernel_launch(void* const* d_in, const int* in_sizes, int n_in,
                              void* d_out, int out_size, void* d_ws, size_t ws_size,
                              hipStream_t stream) {
    (void)in_sizes; (void)n_in; (void)out_size; (void)ws_size;
    const float* X  = (const float*)d_in[0];
    const float* W1 = (const float*)d_in[1];
    const float* b1 = (const float*)d_in[2];
    const float* W2 = (const float*)d_in[3];
    const float* b2 = (const float*)d_in[4];
    float* OUT = (float*)d_out;
    short* W1P = (short*)((char*)d_ws + WS_W1P);
    short* W2P = (short*)((char*)d_ws + WS_W2P);
    short* GP  = (short*)((char*)d_ws + WS_GP);
    float* U   = (float*)((char*)d_ws + WS_U);

    // allow 144.9 KiB dynamic LDS (gfx950 workgroup max is 160 KiB)
    hipFuncSetAttribute(reinterpret_cast<const void*>(k_ode),
                        hipFuncAttributeMaxDynamicSharedMemorySize, LDS_TOTAL);

    k_prep<<<321, 64, 0, stream>>>(W1, W2, b2, W1P, W2P, GP, U);
    k_ode<<<512, 512, LDS_TOTAL, stream>>>(X, W1, b1, b2, W1P, W2P, GP, U, OUT);
}